// Round 1
// 165.860 us; speedup vs baseline: 1.0113x; 1.0113x over previous
//
#include <hip/hip_runtime.h>
#include <cstddef>

// Problem constants
#define Bsz 8
#define Nn  1024
#define Cc  512
#define Hh  8
#define Dd  64
#define EPSF 1e-6f

typedef __attribute__((ext_vector_type(8))) short short8;   // 8 bf16 (4 VGPRs)
typedef __attribute__((ext_vector_type(4))) float floatx4;  // MFMA accumulator

// round-to-nearest-even fp32 -> bf16 (bit pattern in a short)
static __device__ __forceinline__ short f2bf(float f) {
    union { float f; unsigned u; } v; v.f = f;
    unsigned r = (v.u + 0x7FFFu + ((v.u >> 16) & 1u)) >> 16;
    return (short)r;
}
static __device__ __forceinline__ float bf2f(short s) {
    union { unsigned u; float f; } v; v.u = ((unsigned)(unsigned short)s) << 16;
    return v.f;
}

// ---------------------------------------------------------------------------
// XOR-swizzled LDS tiles, linear 16B slots (lane-linear => global_load_lds ok).
// Tile = ROWS x (CHUNKS*8) bf16.  Slot s holds row r=s/CHUNKS, global chunk
// (s%CHUNKS)^(r&7).  Fragment read for row r, logical chunk lc is slot
// r*CHUNKS + (lc^(r&7)) -> bank-balanced ds_read_b128.
// ---------------------------------------------------------------------------
#define GLOAD_LDS16(gp, lp)                                              \
    __builtin_amdgcn_global_load_lds(                                    \
        (const __attribute__((address_space(1))) void*)(gp),             \
        (__attribute__((address_space(3))) void*)(lp), 16, 0, 0)

static __device__ __forceinline__
void stage_tile(short* __restrict__ lds, const short* __restrict__ src,
                int ldsrc, int tid, int CHUNKS, int SLOTS) {
    #pragma unroll
    for (int s = tid; s < SLOTS; s += 256) {
        int r = s / CHUNKS, cs = s % CHUNKS;
        int gc = cs ^ (r & 7);
        GLOAD_LDS16(&src[(size_t)r * ldsrc + gc * 8], &lds[s * 8]);
    }
}
static __device__ __forceinline__
short8 fragT(const short* __restrict__ lds, int CHUNKS, int r, int lc) {
    return *(const short8*)&lds[(r * CHUNKS + (lc ^ (r & 7))) * 8];
}

// raw barrier / counted waits for the 8-phase schedule (no auto vmcnt drain)
#define FENCE() asm volatile("" ::: "memory")
#define BARRIER_RAW() do { FENCE(); __builtin_amdgcn_s_barrier(); FENCE(); } while (0)
#define WAITVM(N) asm volatile("s_waitcnt vmcnt(" #N ")" ::: "memory")

// ---------------------------------------------------------------------------
// Merged prep: blocks [0,2048) cvt x->bf16; [2048,2304) diffusion operator;
// [2304,2496) w_qkv^T; [2496,2560) w_out^T bf16; [2560,3072) mask->bf16.
// ---------------------------------------------------------------------------
__global__ __launch_bounds__(256)
void prep_all(const float* __restrict__ x, const float* __restrict__ mask,
              const float* __restrict__ wq, const float* __restrict__ wo,
              short* __restrict__ xb, short* __restrict__ Ad,
              short* __restrict__ wqT, short* __restrict__ woT,
              short* __restrict__ mbf) {
    __shared__ float t[64][65];
    const int tid = threadIdx.x;
    const int bid = blockIdx.x;

    if (bid < 2048) {                       // x -> bf16, 8 elems/thread
        int idx = bid * 256 + tid;
        const float* s = &x[(size_t)idx * 8];
        union { short h[8]; int4 v; } u;
        #pragma unroll
        for (int j = 0; j < 8; j++) u.h[j] = f2bf(s[j]);
        *(int4*)&xb[(size_t)idx * 8] = u.v;
        return;
    }
    if (bid < 2304) {                       // Ad[n][m] = bf16(I + 0.1*mask^T)
        int idx = bid - 2048;
        const int n0 = (idx & 15) * 64, m0 = (idx >> 4) * 64;
        #pragma unroll
        for (int i = 0; i < 4; i++) {
            int k = i * 256 + tid;
            int r = k >> 4, c4 = (k & 15) * 4;
            *(float4*)&t[r][c4] = *(const float4*)&mask[(size_t)(m0 + r) * Nn + n0 + c4];
        }
        __syncthreads();
        #pragma unroll
        for (int i = 0; i < 4; i++) {
            int k = i * 256 + tid;
            int rr = k >> 4, c4 = (k & 15) * 4;
            union { short h[4]; int2 v; } u;
            #pragma unroll
            for (int j = 0; j < 4; j++) {
                int mm = c4 + j;
                float v = 0.1f * t[mm][rr] + ((n0 + rr) == (m0 + mm) ? 1.0f : 0.0f);
                u.h[j] = f2bf(v);
            }
            *(int2*)&Ad[(size_t)(n0 + rr) * Nn + m0 + c4] = u.v;
        }
        return;
    }
    if (bid < 2496) {                       // wqT[n][k] = bf16(wq[k][n])
        int idx = bid - 2304;
        const int n0 = (idx % 24) * 64, k0 = (idx / 24) * 64;
        #pragma unroll
        for (int i = 0; i < 4; i++) {
            int k = i * 256 + tid;
            int r = k >> 4, c4 = (k & 15) * 4;
            *(float4*)&t[r][c4] = *(const float4*)&wq[(size_t)(k0 + r) * 1536 + n0 + c4];
        }
        __syncthreads();
        #pragma unroll
        for (int i = 0; i < 4; i++) {
            int k = i * 256 + tid;
            int rr = k >> 4, c4 = (k & 15) * 4;
            union { short h[4]; int2 v; } u;
            #pragma unroll
            for (int j = 0; j < 4; j++) u.h[j] = f2bf(t[c4 + j][rr]);
            *(int2*)&wqT[(size_t)(n0 + rr) * 512 + k0 + c4] = u.v;
        }
        return;
    }
    if (bid < 2560) {                        // woT[n][k] = bf16(wo[k][n])
        int idx = bid - 2496;
        const int n0 = (idx & 7) * 64, k0 = (idx >> 3) * 64;
        #pragma unroll
        for (int i = 0; i < 4; i++) {
            int k = i * 256 + tid;
            int r = k >> 4, c4 = (k & 15) * 4;
            *(float4*)&t[r][c4] = *(const float4*)&wo[(size_t)(k0 + r) * 512 + n0 + c4];
        }
        __syncthreads();
        #pragma unroll
        for (int i = 0; i < 4; i++) {
            int k = i * 256 + tid;
            int rr = k >> 4, c4 = (k & 15) * 4;
            union { short h[4]; int2 v; } u;
            #pragma unroll
            for (int j = 0; j < 4; j++) u.h[j] = f2bf(t[c4 + j][rr]);
            *(int2*)&woT[(size_t)(n0 + rr) * 512 + k0 + c4] = u.v;
        }
        return;
    }
    {                                        // mask -> bf16 (original [n][m])
        int idx = (bid - 2560) * 256 + tid;  // 8 elems/thread, 1M total
        const float* s = &mask[(size_t)idx * 8];
        union { short h[8]; int4 v; } u;
        #pragma unroll
        for (int j = 0; j < 8; j++) u.h[j] = f2bf(s[j]);
        *(int4*)&mbf[(size_t)idx * 8] = u.v;
    }
}

// ---------------------------------------------------------------------------
// GEMM1 (8-phase 256x256 template): qkv = xb[8192][512] @ wqT^T, relu+eps on
// cols<1024.  512 threads = 8 waves (2M x 4N), per-wave 128x64 output.
// LDS: 128 KiB dynamic = 2 K-tile buffers x (A 256x64 + B 256x64) bf16.
// Staging halves interleave by the wave-split bit so each half-batch exactly
// covers the next two phases' reads:
//   A half h = rows with bit6==h (m-half of BOTH wave-rows)
//   B half h = rows with bit5==h (n-half of all four wave-cols)
// Per K-tile j: phases (mh,nh) = (0,0),(1,0),(1,1),(0,1).
//   p1 issues next-tile batch alpha=(Ah0,Bh0), p2 issues beta=(Ah1,Bh1).
//   WAITVM(4) before trailing barriers of p1 (drains this tile's beta) and
//   p4 (drains next tile's alpha).  Loads never drain to 0 in the loop (T4).
// ---------------------------------------------------------------------------
static __device__ __forceinline__
void stageA_half(short* __restrict__ buf, const short* __restrict__ gA,
                 int kt, int h, int tid) {
    #pragma unroll
    for (int kk = 0; kk < 2; kk++) {
        int i = tid + kk * 512;             // 0..1023
        int run = i >> 9;                   // 0/1  (row groups 0-63 / 128-191 ...)
        int within = i & 511;
        int r = run * 128 + h * 64 + (within >> 3);
        int c = within & 7;
        int gc = c ^ (r & 7);
        GLOAD_LDS16(gA + (size_t)r * 512 + kt + gc * 8, buf + (r * 8 + c) * 8);
    }
}
static __device__ __forceinline__
void stageB_half(short* __restrict__ buf, const short* __restrict__ gB,
                 int kt, int h, int tid) {
    #pragma unroll
    for (int kk = 0; kk < 2; kk++) {
        int i = tid + kk * 512;
        int run = i >> 8;                   // 0..3 (32-row groups)
        int within = i & 255;
        int r = run * 64 + h * 32 + (within >> 3);
        int c = within & 7;
        int gc = c ^ (r & 7);
        GLOAD_LDS16(gB + (size_t)r * 512 + kt + gc * 8, buf + (r * 8 + c) * 8);
    }
}

template<int MH>
static __device__ __forceinline__
void readA8(const short* __restrict__ bufA, short8 (&aF)[4][2],
            int wr, int l16, int quad) {
    #pragma unroll
    for (int f = 0; f < 4; f++)
        #pragma unroll
        for (int kk = 0; kk < 2; kk++)
            aF[f][kk] = fragT(bufA, 8, wr * 128 + MH * 64 + f * 16 + l16, kk * 4 + quad);
}
template<int NH>
static __device__ __forceinline__
void readB4(const short* __restrict__ bufB, short8 (&bF)[2][2],
            int wc, int l16, int quad) {
    #pragma unroll
    for (int g = 0; g < 2; g++)
        #pragma unroll
        for (int kk = 0; kk < 2; kk++)
            bF[g][kk] = fragT(bufB, 8, wc * 64 + NH * 32 + g * 16 + l16, kk * 4 + quad);
}
template<int MH, int NH>
static __device__ __forceinline__
void mfma16(short8 (&aF)[4][2], short8 (&bF)[2][2], floatx4 (&acc)[8][4]) {
    #pragma unroll
    for (int kk = 0; kk < 2; kk++)
        #pragma unroll
        for (int f = 0; f < 4; f++)
            #pragma unroll
            for (int g = 0; g < 2; g++)
                acc[MH * 4 + f][NH * 2 + g] = __builtin_amdgcn_mfma_f32_16x16x32_bf16(
                    aF[f][kk], bF[g][kk], acc[MH * 4 + f][NH * 2 + g], 0, 0, 0);
}

__global__ __launch_bounds__(512, 2)
void gemm_qkv(const short* __restrict__ xb, const short* __restrict__ wqT,
              short* __restrict__ qT, short* __restrict__ kT,
              short* __restrict__ vT) {
    extern __shared__ short smem[];          // 65536 shorts = 128 KiB

    const int tid = threadIdx.x;
    // XCD-bijective swizzle (192 = 8*24): consecutive wgid share the A-panel.
    const int lin = blockIdx.x;
    const int wgid = (lin & 7) * 24 + (lin >> 3);
    const int mt = wgid / 6, nt = wgid % 6;
    const int m0 = mt * 256, n0 = nt * 256;

    const int wid = tid >> 6, lane = tid & 63;
    const int quad = lane >> 4, l16 = lane & 15;
    const int wr = wid >> 2, wc = wid & 3;

    const short* Ab = xb  + (size_t)m0 * 512;
    const short* Bb = wqT + (size_t)n0 * 512;

    floatx4 acc[8][4];
    #pragma unroll
    for (int i = 0; i < 8; i++)
        #pragma unroll
        for (int j = 0; j < 4; j++) acc[i][j] = (floatx4){0.f, 0.f, 0.f, 0.f};

    short8 aF[4][2], bF[2][2];

    // prologue: stage K-tile 0 (alpha then beta) into buf0
    stageA_half(smem,          Ab, 0, 0, tid);
    stageB_half(smem + 16384,  Bb, 0, 0, tid);
    stageA_half(smem,          Ab, 0, 1, tid);
    stageB_half(smem + 16384,  Bb, 0, 1, tid);
    WAITVM(4); BARRIER_RAW();                 // alpha(0) resident

    for (int j = 0; j < 8; ++j) {            // 8 K-tiles of 64
        const short* cA = smem + (j & 1) * 32768;
        const short* cB = cA + 16384;
        short* nA = smem + ((j + 1) & 1) * 32768;
        short* nB = nA + 16384;
        const int kn = ((j + 1) & 7) * 64;   // wrap: last tile re-stages tile 0

        // p1: quadrant (0,0)
        readA8<0>(cA, aF, wr, l16, quad);
        readB4<0>(cB, bF, wc, l16, quad);
        stageA_half(nA, Ab, kn, 0, tid);
        stageB_half(nB, Bb, kn, 0, tid);
        BARRIER_RAW();
        __builtin_amdgcn_s_setprio(1);
        mfma16<0, 0>(aF, bF, acc);
        __builtin_amdgcn_s_setprio(0);
        WAITVM(4); BARRIER_RAW();            // this tile's beta resident

        // p2: quadrant (1,0)
        readA8<1>(cA, aF, wr, l16, quad);
        stageA_half(nA, Ab, kn, 1, tid);
        stageB_half(nB, Bb, kn, 1, tid);
        BARRIER_RAW();
        __builtin_amdgcn_s_setprio(1);
        mfma16<1, 0>(aF, bF, acc);
        __builtin_amdgcn_s_setprio(0);
        BARRIER_RAW();

        // p3: quadrant (1,1)
        readB4<1>(cB, bF, wc, l16, quad);
        BARRIER_RAW();
        __builtin_amdgcn_s_setprio(1);
        mfma16<1, 1>(aF, bF, acc);
        __builtin_amdgcn_s_setprio(0);
        BARRIER_RAW();

        // p4: quadrant (0,1)
        readA8<0>(cA, aF, wr, l16, quad);
        BARRIER_RAW();
        __builtin_amdgcn_s_setprio(1);
        mfma16<0, 1>(aF, bF, acc);
        __builtin_amdgcn_s_setprio(0);
        WAITVM(4); BARRIER_RAW();            // next tile's alpha resident
    }

    // drain wrapped prefetch before reusing LDS as transpose scratch
    WAITVM(0); BARRIER_RAW();

    // epilogue: per-wave LDS transpose (swizzled) then coalesced stores.
    short* T = smem + wid * 8192;            // 64 n-rows x 128 m (bf16), 16 KiB
    const int doRelu = (n0 < 1024);
    #pragma unroll
    for (int mf = 0; mf < 8; mf++)
        #pragma unroll
        for (int nf = 0; nf < 4; nf++)
            #pragma unroll
            for (int rr = 0; rr < 4; rr++) {
                float v = acc[mf][nf][rr];
                if (doRelu) v = fmaxf(v, 0.0f) + EPSF;
                int row = nf * 16 + l16;
                int col = mf * 16 + quad * 4 + rr;
                T[row * 128 + (col ^ ((row & 15) << 3))] = f2bf(v);
            }
    // wave-private area: within-wave in-order LDS, no barrier needed
    const int gm0 = m0 + wr * 128;
    const int b = gm0 >> 10, m_in0 = gm0 & 1023;
    #pragma unroll
    for (int g = 0; g < 4; g++) {
        int row = (lane >> 2) + g * 16;
        int gn = n0 + wc * 64 + row;
        int part = gn >> 9, ci = gn & 511;
        short* base = (part == 0) ? qT : (part == 1) ? kT : vT;
        short* dst = base + ((size_t)b * 512 + ci) * 1024 + m_in0;
        #pragma unroll
        for (int cc = 0; cc < 4; cc++) {
            int cs = ((lane & 3) + cc * 4) * 8;     // 16B chunk start (shorts)
            *(int4*)&dst[cs] = *(const int4*)&T[row * 128 + (cs ^ ((row & 15) << 3))];
        }
    }
}

// ---------------------------------------------------------------------------
// Diffusion GEMM: qd[b][n][c] = sum_m Ad[n][m] * q[b][m][c]  (BT = qT)
// BK=64 (r12 BK=128 regressed).  XCD swizzle: z (batch-part) on blockIdx.x
// so the 32 blocks sharing one BTb colocate per-XCD.
// ---------------------------------------------------------------------------
__global__ __launch_bounds__(256)
void gemm_diff(const short* __restrict__ Ad, const short* __restrict__ qT,
               const short* __restrict__ kT, short* __restrict__ qd,
               short* __restrict__ kd) {
    __shared__ short smem[16384];
    short* As = smem;
    short* Bs = smem + 8192;

    const int tid = threadIdx.x;
    const int z = blockIdx.x, b = z >> 1, part = z & 1;   // swizzled: z on x
    const short* BTb = (part ? kT : qT) + (size_t)b * 512 * 1024;
    short* outb = (part ? kd : qd) + (size_t)b * 1024 * 512;

    const int c0 = blockIdx.y * 128;
    const int r0 = blockIdx.z * 128;
    const int wave = tid >> 6, lane = tid & 63;
    const int quad = lane >> 4, l16 = lane & 15;
    const int wm = (wave >> 1) * 64, wn = (wave & 1) * 64;

    floatx4 acc[4][4];
    #pragma unroll
    for (int i = 0; i < 4; i++)
        #pragma unroll
        for (int j = 0; j < 4; j++) acc[i][j] = (floatx4){0.f, 0.f, 0.f, 0.f};

    const short* Ab = Ad  + (size_t)r0 * 1024;
    const short* Bb = BTb + (size_t)c0 * 1024;

    for (int k0 = 0; k0 < 1024; k0 += 64) {
        __syncthreads();
        stage_tile(As, Ab + k0, 1024, tid, 8, 1024);
        stage_tile(Bs, Bb + k0, 1024, tid, 8, 1024);
        __syncthreads();
        #pragma unroll
        for (int kh = 0; kh < 2; kh++) {
            short8 a[4], b2[4];
            #pragma unroll
            for (int i = 0; i < 4; i++) a[i]  = fragT(As, 8, wm + i * 16 + l16, kh * 4 + quad);
            #pragma unroll
            for (int i = 0; i < 4; i++) b2[i] = fragT(Bs, 8, wn + i * 16 + l16, kh * 4 + quad);
            #pragma unroll
            for (int mi = 0; mi < 4; mi++)
                #pragma unroll
                for (int ni = 0; ni < 4; ni++)
                    acc[mi][ni] = __builtin_amdgcn_mfma_f32_16x16x32_bf16(
                        a[mi], b2[ni], acc[mi][ni], 0, 0, 0);
        }
    }

    #pragma unroll
    for (int mi = 0; mi < 4; mi++)
        #pragma unroll
        for (int r = 0; r < 4; r++) {
            int n = r0 + wm + mi * 16 + quad * 4 + r;
            #pragma unroll
            for (int ni = 0; ni < 4; ni++) {
                int c = c0 + wn + ni * 16 + l16;
                outb[(size_t)n * 512 + c] = f2bf(acc[mi][ni][r]);
            }
        }
}

// ---------------------------------------------------------------------------
// Masked linear attention (MFMA bf16, flash-style), v8:
// r11-verified body.  XCD swizzle: bh on blockIdx.x so the 8 n0-blocks
// sharing one (b,h)'s K/V land on the same XCD (linear%8 == bh%8) --
// r11 FETCH was 72 MB vs 26 MB unique (K/V replicated across 8 XCD L2s).
// ---------------------------------------------------------------------------
__global__ __launch_bounds__(256)
void attn_mfma(const short* __restrict__ qd, const short* __restrict__ kd,
               const short* __restrict__ vTg, const short* __restrict__ mbf,
               short* __restrict__ abf) {
    __shared__ short qs[8192];   // 128 n-rows x 64 c (8 chunks)
    __shared__ short ks[4096];   //  64 m-rows x 64 c (8 chunks)
    __shared__ short vt[4096];   //  64 d-rows x 64 m (8 chunks)
    __shared__ short ss[8192];   // 128 n-rows x 64 m (8 chunks, wave-private rows)
    __shared__ short ms[8192];   // 128 n-rows x 64 m mask tile (bf16, same swizzle)

    const int tid = threadIdx.x;
    const int bh = blockIdx.x;                // swizzled: bh on x
    const int b = bh >> 3, h = bh & 7;
    const int n0 = blockIdx.y * 128;

    const int wave = tid >> 6, lane = tid & 63;
    const int quad = lane >> 4, l16 = lane & 15;

    const short* Qb = qd + ((size_t)b * Nn + n0) * Cc + h * Dd;        // stride Cc
    const short* Kb = kd + (size_t)b * Nn * Cc + h * Dd;               // stride Cc
    const short* Vb = vTg + ((size_t)b * Cc + h * Dd) * Nn;            // stride Nn
    const short* Mb = mbf + (size_t)n0 * Nn;                           // stride Nn

    stage_tile(qs, Qb, Cc, tid, 8, 1024);
    __syncthreads();                          // qs resident (vmcnt drained)
    short8 aT[2][2];                          // Q-frags (B-operand of S^T mfma)
    #pragma unroll
    for (int t = 0; t < 2; t++) {
        aT[t][0] = fragT(qs, 8, wave * 32 + t * 16 + l16, quad);
        aT[t][1] = fragT(qs, 8, wave * 32 + t * 16 + l16, 4 + quad);
    }

    float dreg[2] = {0.f, 0.f};               // partial denom for n-row = l16 (per t)
    floatx4 nacc[2][4];
    #pragma unroll
    for (int t = 0; t < 2; t++)
        #pragma unroll
        for (int i = 0; i < 4; i++) nacc[t][i] = (floatx4){0.f, 0.f, 0.f, 0.f};

    const int ssrow[2] = { wave * 32 + l16, wave * 32 + 16 + l16 };

    for (int m0 = 0; m0 < Nn; m0 += 64) {
        __syncthreads();                      // prior chunk's readers done
        stage_tile(ks, Kb + (size_t)m0 * Cc, Cc, tid, 8, 512);
        stage_tile(vt, Vb + m0, Nn, tid, 8, 512);
        stage_tile(ms, Mb + m0, Nn, tid, 8, 1024);   // mask tile, async DMA
        __syncthreads();                      // staged data visible

        // phase A: S^T = K Q^T; C: col=l16=n, row=quad*4+r=m
        #pragma unroll
        for (int mt = 0; mt < 4; mt++) {
            const short8 k0f = fragT(ks, 8, mt * 16 + l16, quad);
            const short8 k1f = fragT(ks, 8, mt * 16 + l16, 4 + quad);
            #pragma unroll
            for (int t = 0; t < 2; t++) {
                floatx4 s = (floatx4){0.f, 0.f, 0.f, 0.f};
                s = __builtin_amdgcn_mfma_f32_16x16x32_bf16(k0f, aT[t][0], s, 0, 0, 0);
                s = __builtin_amdgcn_mfma_f32_16x16x32_bf16(k1f, aT[t][1], s, 0, 0, 0);
                const int row = ssrow[t];
                const int c = mt * 16 + quad * 4;
                const int off = (row * 8 + ((c >> 3) ^ (row & 7))) * 8 + (c & 7);
                union { short h[4]; int2 v; } mk;
                mk.v = *(const int2*)&ms[off];          // ds_read_b64, no VMEM
                float sv0 = s[0] * bf2f(mk.h[0]);
                float sv1 = s[1] * bf2f(mk.h[1]);
                float sv2 = s[2] * bf2f(mk.h[2]);
                float sv3 = s[3] * bf2f(mk.h[3]);
                dreg[t] += (sv0 + sv1) + (sv2 + sv3);
                union { short h[4]; int2 v; } pk;
                pk.h[0] = f2bf(sv0); pk.h[1] = f2bf(sv1);
                pk.h[2] = f2bf(sv2); pk.h[3] = f2bf(sv3);
                *(int2*)&ss[off] = pk.v;                // ds_write_b64
            }
        }
        // no barrier: each wave reads exactly the ss rows it wrote
        // (within-wave in-order LDS + compiler lgkmcnt suffices)

        // phase B: num += P @ V.  V-frags shared across both n-tiles.
        short8 p[2][2];
        #pragma unroll
        for (int t = 0; t < 2; t++) {
            p[t][0] = fragT(ss, 8, wave * 32 + t * 16 + l16, quad);
            p[t][1] = fragT(ss, 8, wave * 32 + t * 16 + l16, 4 + quad);
        }
        #pragma unroll
        for (int dt = 0; dt < 4; dt++) {
            const short8 v0 = fragT(vt, 8, dt * 16 + l16, quad);
            const short8 v1 = fragT(vt, 8, dt * 16 + l16, 4 + quad);
            #pragma unroll
            for (int t = 0; t < 2; t++) {
                nacc[t][dt] = __builtin_amdgcn_mfma_f32_16x16x32_bf16(p[t][0], v0, nacc[t][dt], 0, 0, 0);
                nacc[t][dt] = __builtin_amdgcn_mfma_f32_16x16x32_bf16(p[t][1], v1, nacc[t][dt], 0, 0, 0);
            }
        }
    }

    // denom: cross-quad reduce (lanes sharing l16), then per-lane broadcast
    #pragma unroll
    for (int t = 0; t < 2; t++) {
        dreg[t] += __shfl_xor(dreg[t], 16, 64);
        dreg[t] += __shfl_xor(dreg[t], 32, 64);
    }

    #pragma unroll
    for (int t = 0; t < 2; t++)
        #pragma unroll
        for (int r = 0; r < 4; r++) {
            int nloc = quad * 4 + r;          // n within this 16-tile
            float den = __shfl(dreg[t], nloc, 64);
            int n = n0 + wave * 32 + t * 16 + nloc;
            float zr = 1.0f / (den + EPSF);
            #pragma unroll
            for (int dt = 0; dt < 4; dt++) {
                size_t o = ((size_t)b * Nn + n) * Cc + h * Dd + dt * 16 + l16;
                abf[o] = f2bf(nacc[t][dt][r] * zr);
            }
        }
}

// ---------------------------------------------------------------------------
// Output GEMM (single bf16 pass): out = A@W^T + bias (fp32 accumulate).
// BK=64 (r12 BK=128 regressed).  24 KB LDS.
// ---------------------------------------------------------------------------
__global__ __launch_bounds__(256)
void gemm_out(const short* __restrict__ abf, const short* __restrict__ woT,
              const float* __restrict__ bias, float* __restrict__ out) {
    __shared__ short smem[12288];      // 24 KB
    short* As = smem;                  // 64x64
    short* Bs = smem + 4096;           // 128x64

    const int tid = threadIdx.x;
    const int m0 = blockIdx.y * 64;
    const int n0 = blockIdx.x * 128;
    const int wave = tid >> 6, lane = tid & 63;
    const int quad = lane >> 4, l16 = lane & 15;
    const int wm = (wave >> 1) * 32, wn = (wave & 1) * 64;

    floatx4 acc[2][4];
    #pragma unroll
    for (int i = 0; i < 2; i++)
        #pragma unroll
        for (int j = 0; j < 4; j++) acc[i][j] = (floatx4){0.f, 0.f, 0.f, 0.f};

    const short* Ab = abf + (size_t)m0 * 512;
    const short* Bb = woT + (size_t)n0 * 512;

    for (int k0 = 0; k0 < 512; k0 += 64) {
        __syncthreads();
        stage_tile(As, Ab + k0, 512, tid, 8, 512);
        stage_tile(Bs, Bb + k0, 512, tid, 8, 1024);
        __syncthreads();
        #pragma unroll
        for (int kh = 0; kh < 2; kh++) {
            short8 a[2], b[4];
            #pragma unroll
            for (int i = 0; i < 2; i++)
                a[i] = fragT(As, 8, wm + i * 16 + l16, kh * 4 + quad);
            #pragma unroll
            for (int i = 0; i < 4; i++)
                b[i] = fragT(Bs, 8, wn + i * 16 + l16, kh * 4 + quad);
            #pragma unroll
            for (int mi = 0; mi < 2; mi++)
                #pragma unroll
                for (int ni = 0; ni < 4; ni++)
                    acc[mi][ni] = __builtin_amdgcn_mfma_f32_16x16x32_bf16(
                        a[mi], b[ni], acc[mi][ni], 0, 0, 0);
        }
    }

    #pragma unroll
    for (int mi = 0; mi < 2; mi++)
        #pragma unroll
        for (int r = 0; r < 4; r++) {
            int m = m0 + wm + mi * 16 + quad * 4 + r;
            #pragma unroll
            for (int ni = 0; ni < 4; ni++) {
                int n = n0 + wn + ni * 16 + l16;
                out[(size_t)m * 512 + n] = acc[mi][ni][r] + bias[n];
            }
        }
}

// ---------------------------------------------------------------------------
extern "C" void kernel_launch(void* const* d_in, const int* in_sizes, int n_in,
                              void* d_out, int out_size, void* d_ws, size_t ws_size,
                              hipStream_t stream) {
    const float* x     = (const float*)d_in[0];
    const float* mask  = (const float*)d_in[1];
    const float* w_qkv = (const float*)d_in[2];
    const float* w_out = (const float*)d_in[3];
    const float* b_out = (const float*)d_in[4];
    float* out = (float*)d_out;

    char* p = (char*)d_ws;
    short* xb  = (short*)p; p += 8388608;      // [8192][512]
    short* wqT = (short*)p; p += 1572864;      // [1536][512]
    short* Ad  = (short*)p; p += 2097152;      // [1024][1024]
    short* woT = (short*)p; p += 524288;       // [512][512]
    short* mbf = (short*)p; p += 2097152;      // [1024][1024] bf16 mask
    short* qT  = (short*)p; p += 8388608;      // [b][512][1024]
    short* kT  = (short*)p; p += 8388608;
    short* vT  = (short*)p; p += 8388608;
    short* qd  = (short*)p; p += 8388608;      // [b][1024][512]
    short* kd  = (short*)p; p += 8388608;
    short* abf = (short*)p; p += 8388608;      // [8192][512] attn out bf16

    static int attr_set = 0;
    if (!attr_set) {
        hipFuncSetAttribute(reinterpret_cast<const void*>(gemm_qkv),
                            hipFuncAttributeMaxDynamicSharedMemorySize, 131072);
        attr_set = 1;
    }

    dim3 blk(256);

    prep_all  <<<3072, blk, 0, stream>>>(x, mask, w_qkv, w_out,
                                         xb, Ad, wqT, woT, mbf);
    gemm_qkv  <<<dim3(192), dim3(512), 131072, stream>>>(xb, wqT, qT, kT, vT);
    gemm_diff <<<dim3(16, 4, 8), blk, 0, stream>>>(Ad, qT, kT, qd, kd);
    attn_mfma <<<dim3(64, 8),  blk, 0, stream>>>(qd, kd, vT, mbf, abf);
    gemm_out  <<<dim3(4, 128), blk, 0, stream>>>(abf, woT, b_out, out);
}